// Round 1
// baseline (1335.696 us; speedup 1.0000x reference)
//
#include <hip/hip_runtime.h>

#define TOK   8192
#define DD    1024
#define FF    4096
#define EE    8
#define TWOF  8192
#define NSLOT 16384   // TOK * top_k(2)

typedef unsigned short u16;
typedef float  f32x4  __attribute__((ext_vector_type(4)));
typedef __bf16 bf16x8 __attribute__((ext_vector_type(8)));

__device__ __forceinline__ u16 f2b(float f) {
  unsigned u = __builtin_bit_cast(unsigned, f);
  u += 0x7fffu + ((u >> 16) & 1u);   // RNE; inputs finite
  return (u16)(u >> 16);
}

__device__ __forceinline__ void ldslds16(const void* g, void* l) {
  __builtin_amdgcn_global_load_lds((const __attribute__((address_space(1))) void*)g,
                                   (__attribute__((address_space(3))) void*)l, 16, 0, 0);
}

__device__ __forceinline__ int imin(int a, int b) { return a < b ? a : b; }

// ---------------- gate: logits, softmax, top-2, counts ----------------
__global__ void gate_kernel(const float* __restrict__ x, const float* __restrict__ gw,
                            const float* __restrict__ gb, int* __restrict__ counts,
                            int* __restrict__ eidx, int* __restrict__ epos,
                            float* __restrict__ ew) {
  const int wave = threadIdx.x >> 6, lane = threadIdx.x & 63;
  const int t = blockIdx.x * 4 + wave;
  float acc[EE] = {0,0,0,0,0,0,0,0};
  const float* xr = x + (size_t)t * DD;
  for (int d = lane; d < DD; d += 64) {
    float xv = xr[d];
    const float* g = gw + (size_t)d * EE;
#pragma unroll
    for (int e = 0; e < EE; ++e) acc[e] += xv * g[e];
  }
#pragma unroll
  for (int e = 0; e < EE; ++e)
#pragma unroll
    for (int off = 32; off > 0; off >>= 1) acc[e] += __shfl_down(acc[e], off);
  if (lane == 0) {
    float l[EE];
#pragma unroll
    for (int e = 0; e < EE; ++e) l[e] = acc[e] + gb[e];
    int i0 = 0;
    for (int e = 1; e < EE; ++e) if (l[e] > l[i0]) i0 = e;
    int i1 = (i0 == 0) ? 1 : 0;
    for (int e = 0; e < EE; ++e) { if (e == i0) continue; if (l[e] > l[i1]) i1 = e; }
    float m = l[0];
    for (int e = 1; e < EE; ++e) m = fmaxf(m, l[e]);
    float s = 0.f, p[EE];
    for (int e = 0; e < EE; ++e) { p[e] = __expf(l[e] - m); s += p[e]; }
    float w0 = p[i0] / s, w1 = p[i1] / s;
    int p0 = atomicAdd(&counts[i0], 1);
    int p1 = atomicAdd(&counts[i1], 1);
    eidx[2*t] = i0; eidx[2*t+1] = i1;
    epos[2*t] = p0; epos[2*t+1] = p1;
    ew[2*t] = w0;  ew[2*t+1] = w1;
  }
}

__global__ void scan_kernel(const int* __restrict__ counts, int* __restrict__ offs) {
  if (threadIdx.x == 0 && blockIdx.x == 0) {
    int s = 0;
    for (int e = 0; e < EE; ++e) { offs[e] = s; s += counts[e]; }
    offs[EE] = s;
  }
}

__global__ void slot_kernel(const int* __restrict__ eidx, const int* __restrict__ epos,
                            const float* __restrict__ ew, const int* __restrict__ offs,
                            int* __restrict__ s2t, float* __restrict__ swt) {
  int i = blockIdx.x * 256 + threadIdx.x;           // 0..2T-1
  int e = eidx[i];
  int slot = offs[e] + epos[i];
  s2t[slot] = i >> 1;
  swt[slot] = ew[i];
}

// ---------------- conversions ----------------
__global__ void cvtx_kernel(const float* __restrict__ x, u16* __restrict__ xb) {
  int i = blockIdx.x * 256 + threadIdx.x;           // 4 elements each
  float4 v = ((const float4*)x)[i];
  unsigned lo = (unsigned)f2b(v.x) | ((unsigned)f2b(v.y) << 16);
  unsigned hi = (unsigned)f2b(v.z) | ((unsigned)f2b(v.w) << 16);
  ((uint2*)xb)[i] = make_uint2(lo, hi);
}

__global__ void gather_kernel(const u16* __restrict__ xb, const int* __restrict__ s2t,
                              u16* __restrict__ xg) {
  int i = blockIdx.x * 256 + threadIdx.x;           // 16B chunks
  int row = i >> 7, c = i & 127;
  int tok = s2t[row];
  ((int4*)xg)[(size_t)row * 128 + c] = ((const int4*)xb)[(size_t)tok * 128 + c];
}

// transpose-convert weights: dst[seg][n][k] (bf16) = src[seg][k][oc(n)] (f32)
// permute: interleave a/b halves of w1 in 16-col groups (SwiGLU pairing)
__global__ void wt_kernel(const float* __restrict__ srcS, const float* __restrict__ srcR,
                          u16* __restrict__ dst, int K, int N, int permute) {
  __shared__ float tile[32][33];
  const int seg = blockIdx.z;
  const float* src = (seg == 0) ? srcS : srcR + (size_t)(seg - 1) * K * N;
  const int pc0 = blockIdx.x * 32, k0 = blockIdx.y * 32;
  const int tid = threadIdx.x;
  {
    int kk = tid >> 3, j4 = (tid & 7) << 2;
    const float* srow = src + (size_t)(k0 + kk) * N;
#pragma unroll
    for (int q = 0; q < 4; ++q) {
      int n = pc0 + j4 + q;
      int oc = permute ? (((n >> 5) << 4) + (n & 15) + ((n & 16) ? FF : 0)) : n;
      tile[kk][j4 + q] = srow[oc];
    }
  }
  __syncthreads();
  {
    int pp = tid >> 3, kq = (tid & 7) << 2;
    u16* drow = dst + (size_t)seg * N * K + (size_t)(pc0 + pp) * K + k0 + kq;
#pragma unroll
    for (int q = 0; q < 4; ++q) drow[q] = f2b(tile[kq + q][pp]);
  }
}

// ---------------- GEMM1: [rows,1024] x [1024,8192-permuted] -> SwiGLU -> hs bf16 [rows,4096]
__global__ __launch_bounds__(256)
void gemm1_kernel(const u16* __restrict__ xb, const u16* __restrict__ xg,
                  const u16* __restrict__ w1t, const float* __restrict__ sb1,
                  const float* __restrict__ rb1, const int* __restrict__ offs,
                  u16* __restrict__ hs) {
  __shared__ __align__(16) u16 As[128 * 32];
  __shared__ __align__(16) u16 Bs[128 * 32];
  const int seg = blockIdx.z;
  int rowstart, rows, hsbase, atot;
  const u16* A;
  if (seg == 0) { A = xb; rowstart = 0; rows = TOK; hsbase = 0; atot = TOK; }
  else {
    int o0 = offs[seg - 1], o1 = offs[seg];
    A = xg; rowstart = o0; rows = o1 - o0; hsbase = TOK + o0; atot = NSLOT;
  }
  const int tm = blockIdx.y;
  if (tm * 128 >= rows) return;
  const int tn = blockIdx.x;
  const int tid = threadIdx.x, lane = tid & 63, wid = tid >> 6;
  const int wm = wid >> 1, wn = wid & 1;
  const int sr = tid >> 2, sc = (tid & 3) * 8;

  const u16* Ap0 = A + (size_t)imin(rowstart + tm*128 + sr,      atot - 1) * DD + sc;
  const u16* Ap1 = A + (size_t)imin(rowstart + tm*128 + 64 + sr, atot - 1) * DD + sc;
  const u16* Bseg = w1t + (size_t)seg * TWOF * DD;
  const u16* Bp0 = Bseg + (size_t)(tn*128 + sr) * DD + sc;
  const u16* Bp1 = Bseg + (size_t)(tn*128 + 64 + sr) * DD + sc;
  u16* lA0 = As + tid * 8;  u16* lA1 = As + (256 + tid) * 8;
  u16* lB0 = Bs + tid * 8;  u16* lB1 = Bs + (256 + tid) * 8;

  const int fr = lane & 15, fk = (lane >> 4) * 8;
  f32x4 acc[4][4] = {};

  for (int k0 = 0; k0 < DD; k0 += 32) {
    ldslds16(Ap0 + k0, lA0);
    ldslds16(Ap1 + k0, lA1);
    ldslds16(Bp0 + k0, lB0);
    ldslds16(Bp1 + k0, lB1);
    __syncthreads();
    bf16x8 af[4], bq[4];
#pragma unroll
    for (int m = 0; m < 4; ++m) af[m] = *(const bf16x8*)(As + (wm*64 + m*16 + fr)*32 + fk);
#pragma unroll
    for (int n = 0; n < 4; ++n) bq[n] = *(const bf16x8*)(Bs + (wn*64 + n*16 + fr)*32 + fk);
#pragma unroll
    for (int m = 0; m < 4; ++m)
#pragma unroll
      for (int n = 0; n < 4; ++n)
        acc[m][n] = __builtin_amdgcn_mfma_f32_16x16x32_bf16(af[m], bq[n], acc[m][n], 0, 0, 0);
    __syncthreads();
  }

  const int rlim = rows - tm * 128;
  const int rb = wm * 64 + (lane >> 4) * 4;
  const float* b1 = (seg == 0) ? sb1 : rb1 + (size_t)(seg - 1) * TWOF;
  u16* hbase = hs + (size_t)(hsbase + tm * 128) * FF;
  const int fc = tn * 64 + wn * 32 + fr;
#pragma unroll
  for (int np = 0; np < 2; ++np) {
    const int f = fc + np * 16;
    const float ba = b1[f], bb = b1[FF + f];
#pragma unroll
    for (int m = 0; m < 4; ++m)
#pragma unroll
      for (int q = 0; q < 4; ++q) {
        int lr = rb + m * 16 + q;
        if (lr < rlim) {
          float av = acc[m][2*np][q] + ba;
          float bv = acc[m][2*np+1][q] + bb;
          float sv = av / (1.0f + __expf(-av)) * bv;
          hbase[(size_t)lr * FF + f] = f2b(sv);
        }
      }
  }
}

// ---------------- GEMM2: hs [rows,4096] x w2t -> out (store / weighted atomic add)
__global__ __launch_bounds__(256)
void gemm2_kernel(const u16* __restrict__ hs, const u16* __restrict__ w2t,
                  const float* __restrict__ sb2, const float* __restrict__ rb2,
                  const int* __restrict__ offs, const int* __restrict__ s2t,
                  const float* __restrict__ swt, float* __restrict__ out, int routed) {
  __shared__ __align__(16) u16 As[128 * 32];
  __shared__ __align__(16) u16 Bs[128 * 32];
  const int seg = routed ? (int)blockIdx.z + 1 : 0;
  int rowstart, rows, hrow0;
  if (seg == 0) { rowstart = 0; rows = TOK; hrow0 = 0; }
  else {
    int o0 = offs[seg - 1], o1 = offs[seg];
    rowstart = o0; rows = o1 - o0; hrow0 = TOK + o0;
  }
  const int tm = blockIdx.y;
  if (tm * 128 >= rows) return;
  const int tn = blockIdx.x;
  const int tid = threadIdx.x, lane = tid & 63, wid = tid >> 6;
  const int wm = wid >> 1, wn = wid & 1;
  const int sr = tid >> 2, sc = (tid & 3) * 8;

  const u16* Ap0 = hs + (size_t)(hrow0 + tm*128 + sr) * FF + sc;        // hs padded by 128 rows
  const u16* Ap1 = hs + (size_t)(hrow0 + tm*128 + 64 + sr) * FF + sc;
  const u16* Bseg = w2t + (size_t)seg * DD * FF;
  const u16* Bp0 = Bseg + (size_t)(tn*128 + sr) * FF + sc;
  const u16* Bp1 = Bseg + (size_t)(tn*128 + 64 + sr) * FF + sc;
  u16* lA0 = As + tid * 8;  u16* lA1 = As + (256 + tid) * 8;
  u16* lB0 = Bs + tid * 8;  u16* lB1 = Bs + (256 + tid) * 8;

  const int fr = lane & 15, fk = (lane >> 4) * 8;
  f32x4 acc[4][4] = {};

  for (int k0 = 0; k0 < FF; k0 += 32) {
    ldslds16(Ap0 + k0, lA0);
    ldslds16(Ap1 + k0, lA1);
    ldslds16(Bp0 + k0, lB0);
    ldslds16(Bp1 + k0, lB1);
    __syncthreads();
    bf16x8 af[4], bq[4];
#pragma unroll
    for (int m = 0; m < 4; ++m) af[m] = *(const bf16x8*)(As + (wm*64 + m*16 + fr)*32 + fk);
#pragma unroll
    for (int n = 0; n < 4; ++n) bq[n] = *(const bf16x8*)(Bs + (wn*64 + n*16 + fr)*32 + fk);
#pragma unroll
    for (int m = 0; m < 4; ++m)
#pragma unroll
      for (int n = 0; n < 4; ++n)
        acc[m][n] = __builtin_amdgcn_mfma_f32_16x16x32_bf16(af[m], bq[n], acc[m][n], 0, 0, 0);
    __syncthreads();
  }

  const int rlim = rows - tm * 128;
  const int rb = wm * 64 + (lane >> 4) * 4;
  const float* b2 = (seg == 0) ? sb2 : rb2 + (size_t)(seg - 1) * DD;
  const int cc = tn * 128 + wn * 64 + fr;
  float bias[4];
#pragma unroll
  for (int n = 0; n < 4; ++n) bias[n] = b2[cc + n * 16];
#pragma unroll
  for (int m = 0; m < 4; ++m)
#pragma unroll
    for (int q = 0; q < 4; ++q) {
      int lr = rb + m * 16 + q;
      if (lr >= rlim) continue;
      if (seg == 0) {
        float* orow = out + (size_t)(tm * 128 + lr) * DD;
#pragma unroll
        for (int n = 0; n < 4; ++n) orow[cc + n * 16] = acc[m][n][q] + bias[n];
      } else {
        int slot = rowstart + tm * 128 + lr;
        int tokn = s2t[slot];
        float w = swt[slot];
        float* orow = out + (size_t)tokn * DD;
#pragma unroll
        for (int n = 0; n < 4; ++n) atomicAdd(&orow[cc + n * 16], w * (acc[m][n][q] + bias[n]));
      }
    }
}

// ---------------- launch ----------------
extern "C" void kernel_launch(void* const* d_in, const int* in_sizes, int n_in,
                              void* d_out, int out_size, void* d_ws, size_t ws_size,
                              hipStream_t stream) {
  const float* x   = (const float*)d_in[0];
  const float* gw  = (const float*)d_in[1];
  const float* gb  = (const float*)d_in[2];
  const float* sw1 = (const float*)d_in[3];
  const float* sb1 = (const float*)d_in[4];
  const float* sw2 = (const float*)d_in[5];
  const float* sb2 = (const float*)d_in[6];
  const float* rw1 = (const float*)d_in[7];
  const float* rb1 = (const float*)d_in[8];
  const float* rw2 = (const float*)d_in[9];
  const float* rb2 = (const float*)d_in[10];
  float* out = (float*)d_out;

  char* p = (char*)d_ws;
  auto alloc = [&](size_t bytes) { char* r = p; p += (bytes + 255) & ~(size_t)255; return r; };
  int*   counts = (int*)alloc(EE * 4);
  int*   offs   = (int*)alloc((EE + 1) * 4);
  int*   eidx   = (int*)alloc((size_t)2 * TOK * 4);
  int*   epos   = (int*)alloc((size_t)2 * TOK * 4);
  float* ew     = (float*)alloc((size_t)2 * TOK * 4);
  int*   s2t    = (int*)alloc((size_t)NSLOT * 4);
  float* swt    = (float*)alloc((size_t)NSLOT * 4);
  u16*   xb     = (u16*)alloc((size_t)TOK * DD * 2);
  u16*   xg     = (u16*)alloc((size_t)NSLOT * DD * 2);
  u16*   w1t    = (u16*)alloc((size_t)9 * TWOF * DD * 2);
  u16*   w2t    = (u16*)alloc((size_t)9 * DD * FF * 2);
  u16*   hs     = (u16*)alloc((size_t)(TOK + NSLOT + 128) * FF * 2);

  hipMemsetAsync(counts, 0, EE * 4, stream);
  gate_kernel<<<TOK / 4, 256, 0, stream>>>(x, gw, gb, counts, eidx, epos, ew);
  scan_kernel<<<1, 64, 0, stream>>>(counts, offs);
  slot_kernel<<<(2 * TOK) / 256, 256, 0, stream>>>(eidx, epos, ew, offs, s2t, swt);
  cvtx_kernel<<<(TOK * DD / 4) / 256, 256, 0, stream>>>(x, xb);
  gather_kernel<<<(NSLOT * 128) / 256, 256, 0, stream>>>(xb, s2t, xg);
  wt_kernel<<<dim3(TWOF / 32, DD / 32, 9), 256, 0, stream>>>(sw1, rw1, w1t, DD, TWOF, 1);
  wt_kernel<<<dim3(DD / 32, FF / 32, 9), 256, 0, stream>>>(sw2, rw2, w2t, FF, DD, 0);
  gemm1_kernel<<<dim3(TWOF / 128, 64, 9), 256, 0, stream>>>(xb, xg, w1t, sb1, rb1, offs, hs);
  gemm2_kernel<<<dim3(DD / 128, 64, 1), 256, 0, stream>>>(hs, w2t, sb2, rb2, offs, s2t, swt, out, 0);
  gemm2_kernel<<<dim3(DD / 128, 64, 8), 256, 0, stream>>>(hs, w2t, sb2, rb2, offs, s2t, swt, out, 1);
}